// Round 1
// baseline (12890.425 us; speedup 1.0000x reference)
//
#include <hip/hip_runtime.h>
#include <hip/hip_fp16.h>

#define NB 2
#define D 32
#define H 128
#define NSTEPS 8
#define BT 256   // threads per block

__device__ __forceinline__ float fast_tanh(float v) {
    // tanh(v) = (e^{2v}-1)/(e^{2v}+1), clamped so exp never overflows.
    v = fminf(15.f, fmaxf(-15.f, v));
    float e = __expf(2.f * v);
    return (e - 1.f) / (e + 1.f);
}

// One MLP_ODE evaluation: kout = W3 tanh(W2 tanh(W1 [t,y] + b1) + b2) + b3
// h1 lives in LDS (__half, transposed [i][tid] so the 64-lane access is
// conflict-free: byte addr = i*512 + 2*tid -> bank (tid>>1)&31, 2 lanes/word).
// Each thread only touches its own column -> no __syncthreads needed.
__device__ __forceinline__ void mlp_eval(
    float t, const float* __restrict__ y, float* __restrict__ kout, int tid,
    __half* __restrict__ h1s,
    const float* __restrict__ W1b, const float* __restrict__ b1b,
    const float* __restrict__ W2b, const float* __restrict__ b2b,
    const float* __restrict__ W3b, const float* __restrict__ b3b)
{
    // ---- layer 1: z1[j] = b1[j] + t * sum_{i<32} W1[i][j] + sum_i y[i] W1[32+i][j]
    for (int jb = 0; jb < H; jb += 4) {
        float a0 = b1b[jb+0], a1 = b1b[jb+1], a2 = b1b[jb+2], a3 = b1b[jb+3];
        float s0 = 0.f, s1 = 0.f, s2 = 0.f, s3 = 0.f;
        #pragma unroll
        for (int i = 0; i < D; ++i) {     // t-broadcast rows 0..31
            const float4 w = *(const float4*)(W1b + (size_t)i*H + jb);
            s0 += w.x; s1 += w.y; s2 += w.z; s3 += w.w;
        }
        a0 = fmaf(t, s0, a0); a1 = fmaf(t, s1, a1);
        a2 = fmaf(t, s2, a2); a3 = fmaf(t, s3, a3);
        #pragma unroll
        for (int i = 0; i < D; ++i) {     // x rows 32..63
            const float4 w = *(const float4*)(W1b + (size_t)(D+i)*H + jb);
            a0 = fmaf(y[i], w.x, a0); a1 = fmaf(y[i], w.y, a1);
            a2 = fmaf(y[i], w.z, a2); a3 = fmaf(y[i], w.w, a3);
        }
        h1s[(jb+0)*BT + tid] = __float2half(fast_tanh(a0));
        h1s[(jb+1)*BT + tid] = __float2half(fast_tanh(a1));
        h1s[(jb+2)*BT + tid] = __float2half(fast_tanh(a2));
        h1s[(jb+3)*BT + tid] = __float2half(fast_tanh(a3));
    }

    // ---- layers 2+3 fused: never materialize h2; accumulate o[] as we go.
    float o[D];
    #pragma unroll
    for (int d = 0; d < D; ++d) o[d] = b3b[d];

    for (int jb = 0; jb < H; jb += 8) {
        float a[8];
        #pragma unroll
        for (int q = 0; q < 8; ++q) a[q] = b2b[jb+q];
        for (int i = 0; i < H; ++i) {
            const float h = __half2float(h1s[i*BT + tid]);
            const float4 w0 = *(const float4*)(W2b + (size_t)i*H + jb);
            const float4 w1 = *(const float4*)(W2b + (size_t)i*H + jb + 4);
            a[0] = fmaf(h, w0.x, a[0]); a[1] = fmaf(h, w0.y, a[1]);
            a[2] = fmaf(h, w0.z, a[2]); a[3] = fmaf(h, w0.w, a[3]);
            a[4] = fmaf(h, w1.x, a[4]); a[5] = fmaf(h, w1.y, a[5]);
            a[6] = fmaf(h, w1.z, a[6]); a[7] = fmaf(h, w1.w, a[7]);
        }
        #pragma unroll
        for (int q = 0; q < 8; ++q) a[q] = fast_tanh(a[q]);
        #pragma unroll
        for (int q = 0; q < 8; ++q) {
            #pragma unroll
            for (int db = 0; db < D; db += 4) {
                const float4 w = *(const float4*)(W3b + (size_t)(jb+q)*D + db);
                o[db+0] = fmaf(a[q], w.x, o[db+0]);
                o[db+1] = fmaf(a[q], w.y, o[db+1]);
                o[db+2] = fmaf(a[q], w.z, o[db+2]);
                o[db+3] = fmaf(a[q], w.w, o[db+3]);
            }
        }
    }
    #pragma unroll
    for (int d = 0; d < D; ++d) kout[d] = o[d];
}

__global__ __launch_bounds__(BT, 1) void ffjord_kernel(
    const float* __restrict__ x_in,
    const float* __restrict__ W1, const float* __restrict__ b1,
    const float* __restrict__ W2, const float* __restrict__ b2,
    const float* __restrict__ W3, const float* __restrict__ b3,
    float* __restrict__ out, int n)
{
    __shared__ __half h1s[H * BT];   // 64 KB, thread-private columns
    const int tid = threadIdx.x;
    const long s = (long)blockIdx.x * BT + tid;
    if (s >= n) return;

    float x[D];
    #pragma unroll
    for (int d = 0; d < D; ++d) x[d] = x_in[s*(long)D + d];

    const float dt = 1.f / NSTEPS;

    for (int bij = 0; bij < NB; ++bij) {
        const float* W1b = W1 + (size_t)bij * 2*D*H;
        const float* b1b = b1 + bij*H;
        const float* W2b = W2 + (size_t)bij * H*H;
        const float* b2b = b2 + bij*H;
        const float* W3b = W3 + (size_t)bij * H*D;
        const float* b3b = b3 + bij*D;

        for (int step = 0; step < NSTEPS; ++step) {
            const float t0 = step * dt;
            float k1[D], k2[D], k3[D], k4[D], k5[D], y[D];

            mlp_eval(t0, x, k1, tid, h1s, W1b, b1b, W2b, b2b, W3b, b3b);
            #pragma unroll
            for (int d = 0; d < D; ++d)
                y[d] = fmaf(dt * (1.f/5.f), k1[d], x[d]);

            mlp_eval(t0 + dt*(1.f/5.f), y, k2, tid, h1s, W1b, b1b, W2b, b2b, W3b, b3b);
            #pragma unroll
            for (int d = 0; d < D; ++d)
                y[d] = x[d] + dt*((3.f/40.f)*k1[d] + (9.f/40.f)*k2[d]);

            mlp_eval(t0 + dt*(3.f/10.f), y, k3, tid, h1s, W1b, b1b, W2b, b2b, W3b, b3b);
            #pragma unroll
            for (int d = 0; d < D; ++d)
                y[d] = x[d] + dt*((44.f/45.f)*k1[d] - (56.f/15.f)*k2[d] + (32.f/9.f)*k3[d]);

            mlp_eval(t0 + dt*(4.f/5.f), y, k4, tid, h1s, W1b, b1b, W2b, b2b, W3b, b3b);
            #pragma unroll
            for (int d = 0; d < D; ++d)
                y[d] = x[d] + dt*((19372.f/6561.f)*k1[d] - (25360.f/2187.f)*k2[d]
                                + (64448.f/6561.f)*k3[d] - (212.f/729.f)*k4[d]);

            mlp_eval(t0 + dt*(8.f/9.f), y, k5, tid, h1s, W1b, b1b, W2b, b2b, W3b, b3b);
            #pragma unroll
            for (int d = 0; d < D; ++d)
                y[d] = x[d] + dt*((9017.f/3168.f)*k1[d] - (355.f/33.f)*k2[d]
                                + (46732.f/5247.f)*k3[d] + (49.f/176.f)*k4[d]
                                - (5103.f/18656.f)*k5[d]);

            // k6 reuses k2's registers (k2 is dead after this point)
            mlp_eval(t0 + dt, y, k2, tid, h1s, W1b, b1b, W2b, b2b, W3b, b3b);
            #pragma unroll
            for (int d = 0; d < D; ++d)
                x[d] = x[d] + dt*((35.f/384.f)*k1[d] + (500.f/1113.f)*k3[d]
                                + (125.f/192.f)*k4[d] - (2187.f/6784.f)*k5[d]
                                + (11.f/84.f)*k2[d]);
        }
    }

    #pragma unroll
    for (int d = 0; d < D; ++d) out[s*(long)D + d] = x[d];
}

extern "C" void kernel_launch(void* const* d_in, const int* in_sizes, int n_in,
                              void* d_out, int out_size, void* d_ws, size_t ws_size,
                              hipStream_t stream) {
    const float* x  = (const float*)d_in[0];
    const float* W1 = (const float*)d_in[1];
    const float* b1 = (const float*)d_in[2];
    const float* W2 = (const float*)d_in[3];
    const float* b2 = (const float*)d_in[4];
    const float* W3 = (const float*)d_in[5];
    const float* b3 = (const float*)d_in[6];
    float* out = (float*)d_out;

    const int n = in_sizes[0] / D;            // 65536 samples
    const int grid = (n + BT - 1) / BT;       // 256 blocks
    ffjord_kernel<<<grid, BT, 0, stream>>>(x, W1, b1, W2, b2, W3, b3, out, n);
}

// Round 3
// 950.247 us; speedup vs baseline: 13.5653x; 13.5653x over previous
//
#include <hip/hip_runtime.h>

#define NB 2
#define D 32
#define H 128
#define NSTEPS 8

typedef _Float16 f16;
typedef _Float16 f16x2 __attribute__((ext_vector_type(2)));
typedef _Float16 f16x4 __attribute__((ext_vector_type(4)));
typedef _Float16 f16x8 __attribute__((ext_vector_type(8)));
typedef float    f32x4 __attribute__((ext_vector_type(4)));

// ---- LDS layout (bytes). Total 145536 <= 163840.
#define OFF_WT1 0         // f16 [128][40]   W1^T rows 32..63 (x part), k-pad 32->40
#define OFF_WT2 10240     // f16 [128][136]  W2^T, k-pad 128->136
#define OFF_WT3 45056     // f16 [32][136]   W3^T
#define OFF_S1  53760     // f32 [128]  column sums of W1 rows 0..31 (t-broadcast fold)
#define OFF_B1  54272     // f32 [128]
#define OFF_B2  54784     // f32 [128]
#define OFF_B3  55296     // f32 [32]
#define OFF_XS  55424     // f16 [256][40]   current MLP input y, [sample][k]
#define OFF_H   75904     // f16 [256][136]  h1/h2; per-wave fp32 k-buffer aliased inside
#define SMEM_BYTES 145536

__device__ __forceinline__ float fast_tanh(float v) {
    // tanh(v) = 1 - 2/(1+e^{2v}); exp saturates (inf/0) -> exact +-1 limits.
    float e = __expf(2.f * v);
    return 1.f - 2.f * __builtin_amdgcn_rcpf(1.f + e);
}

__device__ __forceinline__ f16x2 pk(float a, float b) {
    return __builtin_bit_cast(f16x2, __builtin_amdgcn_cvt_pkrtz(a, b));
}

__device__ const float CC[6] = {0.f, 0.2f, 0.3f, 0.8f, 8.f/9.f, 1.f};

__global__ __launch_bounds__(256, 1) void ffjord_mfma(
    const float* __restrict__ x_in,
    const float* __restrict__ W1, const float* __restrict__ b1,
    const float* __restrict__ W2, const float* __restrict__ b2,
    const float* __restrict__ W3, const float* __restrict__ b3,
    float* __restrict__ out)
{
    extern __shared__ char smem[];
    f16*   WT1 = (f16*)(smem + OFF_WT1);
    f16*   WT2 = (f16*)(smem + OFF_WT2);
    f16*   WT3 = (f16*)(smem + OFF_WT3);
    float* S1  = (float*)(smem + OFF_S1);
    float* B1s = (float*)(smem + OFF_B1);
    float* B2s = (float*)(smem + OFF_B2);
    float* B3s = (float*)(smem + OFF_B3);
    f16*   XS  = (f16*)(smem + OFF_XS);
    f16*   Hs  = (f16*)(smem + OFF_H);

    const int tid  = threadIdx.x;
    const int mrow = tid & 15;        // A's m (out-feature row), B's n (sample)
    const int quad = (tid >> 4) & 3;  // k-quad within wave
    const int wid  = tid >> 6;
    const int srow = wid * 64;        // wave's first block-local sample
    // wave-local fp32 k-buffer [64][36], aliased onto this wave's Hs region
    // (64*144=9216 <= 64*272; h2 is reg-preloaded before k writes -> safe)
    char*  KSb  = smem + OFF_H + srow * 272;
    float* KSme = (float*)(smem + OFF_H + wid * 17408) + (tid & 63) * 36;

    const long g = (long)blockIdx.x * 256 + tid;   // my sample

    float x[D], k1[D], k2[D], k3[D], k4[D], k5[D];
    #pragma unroll
    for (int d4 = 0; d4 < D/4; ++d4) {
        f32x4 v = *(const f32x4*)(x_in + g*D + d4*4);
        x[d4*4+0]=v[0]; x[d4*4+1]=v[1]; x[d4*4+2]=v[2]; x[d4*4+3]=v[3];
    }
    const float dt = 0.125f;

    for (int bij = 0; bij < NB; ++bij) {
        const float* W1b = W1 + (size_t)bij * 2*D*H;
        const float* b1b = b1 + bij*H;
        const float* W2b = W2 + (size_t)bij * H*H;
        const float* b2b = b2 + bij*H;
        const float* W3b = W3 + (size_t)bij * H*D;
        const float* b3b = b3 + bij*D;

        __syncthreads();   // previous bijector's waves done with weights
        // ---- stage weights (transposed, f16) ----
        for (int idx = tid; idx < H*D; idx += 256) {      // WT1: n=128, k=32
            int n = idx & 127, k = idx >> 7;
            WT1[n*40 + k] = (f16)W1b[(size_t)(D + k)*H + n];
        }
        for (int n = tid; n < H; n += 256) {
            float s = 0.f;
            for (int i = 0; i < D; ++i) s += W1b[(size_t)i*H + n];
            S1[n] = s; B1s[n] = b1b[n]; B2s[n] = b2b[n];
        }
        for (int idx = tid; idx < H*H; idx += 256) {      // WT2
            int n = idx & 127, k = idx >> 7;
            WT2[n*136 + k] = (f16)W2b[(size_t)k*H + n];
        }
        for (int idx = tid; idx < D*H; idx += 256) {      // WT3: n=32, k=128
            int n = idx & 31, k = idx >> 5;
            WT3[n*136 + k] = (f16)W3b[(size_t)k*D + n];
        }
        if (tid < D) B3s[tid] = b3b[tid];
        __syncthreads();

        // XS <- x (f16)
        #pragma unroll
        for (int d8 = 0; d8 < 4; ++d8) {
            union { f16x8 v; f16x2 h[4]; } u;
            u.h[0] = pk(x[d8*8+0], x[d8*8+1]);
            u.h[1] = pk(x[d8*8+2], x[d8*8+3]);
            u.h[2] = pk(x[d8*8+4], x[d8*8+5]);
            u.h[3] = pk(x[d8*8+6], x[d8*8+7]);
            *(f16x8*)&XS[tid*40 + d8*8] = u.v;
        }

        for (int step = 0; step < NSTEPS; ++step) {
            const float t0 = step * dt;
            for (int s = 0; s < 6; ++s) {
                const float te = t0 + dt * CC[s];

                // ================= EVAL: XS -> KS =================
                // layer 1 (K=32): D1[feat][samp] = W1T x y^T, bias+t*S1 folded into C
                f16x8 bx[4];
                #pragma unroll
                for (int mt = 0; mt < 4; ++mt)
                    bx[mt] = *(const f16x8*)&XS[(srow + mt*16 + mrow)*40 + quad*8];
                #pragma unroll 1
                for (int nt = 0; nt < 8; ++nt) {
                    const int nb = nt*16 + quad*4;
                    f32x4 bias = *(const f32x4*)&B1s[nb];
                    f32x4 s1v  = *(const f32x4*)&S1[nb];
                    f32x4 cini;
                    #pragma unroll
                    for (int r = 0; r < 4; ++r) cini[r] = fmaf(te, s1v[r], bias[r]);
                    f16x8 wf = *(const f16x8*)&WT1[(nt*16 + mrow)*40 + quad*8];
                    #pragma unroll
                    for (int mt = 0; mt < 4; ++mt) {
                        f32x4 acc = __builtin_amdgcn_mfma_f32_16x16x32_f16(wf, bx[mt], cini, 0, 0, 0);
                        union { f16x4 v; f16x2 h[2]; } u;
                        u.h[0] = pk(fast_tanh(acc[0]), fast_tanh(acc[1]));
                        u.h[1] = pk(fast_tanh(acc[2]), fast_tanh(acc[3]));
                        *(f16x4*)&Hs[(srow + mt*16 + mrow)*136 + nt*16 + quad*4] = u.v;
                    }
                }
                // layer 2 (K=128)
                f16x8 hf[4][4];
                #pragma unroll
                for (int mt = 0; mt < 4; ++mt)
                    #pragma unroll
                    for (int kt = 0; kt < 4; ++kt)
                        hf[mt][kt] = *(const f16x8*)&Hs[(srow + mt*16 + mrow)*136 + kt*32 + quad*8];
                #pragma unroll 1
                for (int nt = 0; nt < 8; ++nt) {
                    f32x4 bias = *(const f32x4*)&B2s[nt*16 + quad*4];
                    f16x8 wf2[4];
                    #pragma unroll
                    for (int kt = 0; kt < 4; ++kt)
                        wf2[kt] = *(const f16x8*)&WT2[(nt*16 + mrow)*136 + kt*32 + quad*8];
                    #pragma unroll
                    for (int mt = 0; mt < 4; ++mt) {
                        f32x4 acc = bias;
                        #pragma unroll
                        for (int kt = 0; kt < 4; ++kt)
                            acc = __builtin_amdgcn_mfma_f32_16x16x32_f16(wf2[kt], hf[mt][kt], acc, 0, 0, 0);
                        union { f16x4 v; f16x2 h[2]; } u;
                        u.h[0] = pk(fast_tanh(acc[0]), fast_tanh(acc[1]));
                        u.h[1] = pk(fast_tanh(acc[2]), fast_tanh(acc[3]));
                        *(f16x4*)&Hs[(srow + mt*16 + mrow)*136 + nt*16 + quad*4] = u.v;
                    }
                }
                // layer 3 (K=128, Nout=32) -> KS (fp32, wave-local)
                f16x8 h2f[4][4];
                #pragma unroll
                for (int mt = 0; mt < 4; ++mt)
                    #pragma unroll
                    for (int kt = 0; kt < 4; ++kt)
                        h2f[mt][kt] = *(const f16x8*)&Hs[(srow + mt*16 + mrow)*136 + kt*32 + quad*8];
                #pragma unroll 1
                for (int nt = 0; nt < 2; ++nt) {
                    f32x4 bias = *(const f32x4*)&B3s[nt*16 + quad*4];
                    f16x8 wf3[4];
                    #pragma unroll
                    for (int kt = 0; kt < 4; ++kt)
                        wf3[kt] = *(const f16x8*)&WT3[(nt*16 + mrow)*136 + kt*32 + quad*8];
                    #pragma unroll
                    for (int mt = 0; mt < 4; ++mt) {
                        f32x4 acc = bias;
                        #pragma unroll
                        for (int kt = 0; kt < 4; ++kt)
                            acc = __builtin_amdgcn_mfma_f32_16x16x32_f16(wf3[kt], h2f[mt][kt], acc, 0, 0, 0);
                        *(f32x4*)(KSb + (mt*16 + mrow)*144 + (nt*16 + quad*4)*4) = acc;
                    }
                }

                // ================= COMBINE (per-thread, own sample) =================
                float y[D];
                #define LOADK(karr) do { \
                    _Pragma("unroll") \
                    for (int d4 = 0; d4 < 8; ++d4) { \
                        f32x4 v = *(const f32x4*)&KSme[d4*4]; \
                        karr[d4*4+0]=v[0]; karr[d4*4+1]=v[1]; karr[d4*4+2]=v[2]; karr[d4*4+3]=v[3]; \
                    } } while (0)
                switch (s) {
                case 0: {
                    LOADK(k1);
                    #pragma unroll
                    for (int d = 0; d < D; ++d) y[d] = fmaf(dt*0.2f, k1[d], x[d]);
                } break;
                case 1: {
                    LOADK(k2);
                    #pragma unroll
                    for (int d = 0; d < D; ++d)
                        y[d] = x[d] + dt*((3.f/40.f)*k1[d] + (9.f/40.f)*k2[d]);
                } break;
                case 2: {
                    LOADK(k3);
                    #pragma unroll
                    for (int d = 0; d < D; ++d)
                        y[d] = x[d] + dt*((44.f/45.f)*k1[d] - (56.f/15.f)*k2[d] + (32.f/9.f)*k3[d]);
                } break;
                case 3: {
                    LOADK(k4);
                    #pragma unroll
                    for (int d = 0; d < D; ++d)
                        y[d] = x[d] + dt*((19372.f/6561.f)*k1[d] - (25360.f/2187.f)*k2[d]
                                        + (64448.f/6561.f)*k3[d] - (212.f/729.f)*k4[d]);
                } break;
                case 4: {
                    LOADK(k5);
                    #pragma unroll
                    for (int d = 0; d < D; ++d)
                        y[d] = x[d] + dt*((9017.f/3168.f)*k1[d] - (355.f/33.f)*k2[d]
                                        + (46732.f/5247.f)*k3[d] + (49.f/176.f)*k4[d]
                                        - (5103.f/18656.f)*k5[d]);
                } break;
                default: {
                    float k6[D];
                    LOADK(k6);
                    #pragma unroll
                    for (int d = 0; d < D; ++d) {
                        x[d] = x[d] + dt*((35.f/384.f)*k1[d] + (500.f/1113.f)*k3[d]
                                        + (125.f/192.f)*k4[d] - (2187.f/6784.f)*k5[d]
                                        + (11.f/84.f)*k6[d]);
                        y[d] = x[d];
                    }
                } break;
                }
                // compiler memory barrier: KS float loads above must not be
                // reordered with next stage's f16 Hs stores (TBAA no-alias pair)
                asm volatile("" ::: "memory");

                // XS <- y (f16) for next eval
                #pragma unroll
                for (int d8 = 0; d8 < 4; ++d8) {
                    union { f16x8 v; f16x2 h[4]; } u;
                    u.h[0] = pk(y[d8*8+0], y[d8*8+1]);
                    u.h[1] = pk(y[d8*8+2], y[d8*8+3]);
                    u.h[2] = pk(y[d8*8+4], y[d8*8+5]);
                    u.h[3] = pk(y[d8*8+6], y[d8*8+7]);
                    *(f16x8*)&XS[tid*40 + d8*8] = u.v;
                }
            } // stages
        } // steps
    } // bijectors

    #pragma unroll
    for (int d4 = 0; d4 < D/4; ++d4) {
        f32x4 v; v[0]=x[d4*4]; v[1]=x[d4*4+1]; v[2]=x[d4*4+2]; v[3]=x[d4*4+3];
        *(f32x4*)(out + g*D + d4*4) = v;
    }
}

extern "C" void kernel_launch(void* const* d_in, const int* in_sizes, int n_in,
                              void* d_out, int out_size, void* d_ws, size_t ws_size,
                              hipStream_t stream) {
    (void)d_ws; (void)ws_size; (void)n_in; (void)out_size;
    const float* x  = (const float*)d_in[0];
    const float* W1 = (const float*)d_in[1];
    const float* b1 = (const float*)d_in[2];
    const float* W2 = (const float*)d_in[3];
    const float* b2 = (const float*)d_in[4];
    const float* W3 = (const float*)d_in[5];
    const float* b3 = (const float*)d_in[6];
    float* out = (float*)d_out;

    (void)hipFuncSetAttribute((const void*)ffjord_mfma,
                        hipFuncAttributeMaxDynamicSharedMemorySize, SMEM_BYTES);

    const int n = in_sizes[0] / D;          // 65536 samples
    const int grid = n / 256;               // 256 blocks, exact
    ffjord_mfma<<<grid, 256, SMEM_BYTES, stream>>>(x, W1, b1, W2, b2, W3, b3, out);
}